// Round 11
// baseline (79.415 us; speedup 1.0000x reference)
//
#include <hip/hip_runtime.h>

#define K_SPARSE 64
#define COLS     4096
#define NTHREADS 128
#define EPT      (COLS / NTHREADS)   // 32 elements per thread
#define VPT      (EPT / 4)           // 8 float4 loads per thread
#define FAST_CAP 1024                // fast-path candidate cap
#define LIST_CAP (FAST_CAP + 8)      // + pad for b128 tail reads

typedef float    nfloat4 __attribute__((ext_vector_type(4)));
typedef unsigned nuint4  __attribute__((ext_vector_type(4)));

// Order-preserving fp32 -> uint32 mapping (ascending float order == ascending uint order)
__device__ __forceinline__ unsigned mapf(unsigned b) {
    return (b & 0x80000000u) ? ~b : (b | 0x80000000u);
}
__device__ __forceinline__ float unmapf(unsigned u) {
    unsigned b = (u & 0x80000000u) ? (u ^ 0x80000000u) : ~u;
    return __uint_as_float(b);
}

__global__ __launch_bounds__(NTHREADS, 8)   // cap VGPR<=64 -> 8 waves/EU, 16 blocks/CU
void ksparse_select(const float* __restrict__ x, float* __restrict__ out, int rows)
{
    const int row = blockIdx.x;
    if (row >= rows) return;
    const int t    = threadIdx.x;
    const int lane = t & 63;
    const int w    = t >> 6;          // wave id 0..1

    __shared__ __align__(16) unsigned list[LIST_CAP];
    __shared__ unsigned wtot[2];
    __shared__ unsigned s_kth;

    const float4* __restrict__ xrow =
        reinterpret_cast<const float4*>(x) + (size_t)row * (COLS / 4);
    nfloat4* __restrict__ orow =
        reinterpret_cast<nfloat4*>(out) + (size_t)row * (COLS / 4);

    // Whole row into registers as order-mapped uints only (floats reconstructed
    // at store time via unmapf -> exact bit round-trip; saves ~32 VGPR).
    unsigned u[EPT];
#pragma unroll
    for (int i = 0; i < VPT; ++i) {
        float4 v = xrow[t + i * NTHREADS];
        u[i * 4 + 0] = mapf(__float_as_uint(v.x));
        u[i * 4 + 1] = mapf(__float_as_uint(v.y));
        u[i * 4 + 2] = mapf(__float_as_uint(v.z));
        u[i * 4 + 3] = mapf(__float_as_uint(v.w));
    }

    // --- Phase 1: threshold rung ladder. For N(0,1) rows the first rung
    // (T=1.9 -> c~118) always suffices; rungs only affect speed, not
    // correctness (exactness comes from the select below / the fallback).
    // mapf(1.9f)=0xBFF33333, mapf(0.9f)=0xBF666666, mapf(-FLT_MAX)~=0x00800000.
    unsigned uT = 0, cnt = 0, base = 0, c = 0;
    for (int r = 0; r < 4; ++r) {
        uT = (r == 0) ? 0xBFF33333u
           : (r == 1) ? 0xBF666666u
           : (r == 2) ? 0x00800000u : 0u;
        cnt = 0;
#pragma unroll
        for (int i = 0; i < EPT; ++i) cnt += (u[i] > uT) ? 1u : 0u;

        // Wave-level inclusive prefix scan (no barriers).
        unsigned s = cnt;
#pragma unroll
        for (int off = 1; off < 64; off <<= 1) {
            unsigned v = __shfl_up(s, off, 64);
            if (lane >= off) s += v;
        }
        if (lane == 63) wtot[w] = s;   // wave total
        __syncthreads();               // B1: wtot visible
        const unsigned c0 = wtot[0], c1 = wtot[1];
        c = c0 + c1;
        if (c >= K_SPARSE + 1 || r == 3) {
            base = (w > 0 ? c0 : 0u) + s - cnt;  // block-wide exclusive prefix
            break;
        }
        __syncthreads();               // B1b: wtot consumed before next rung rewrites
    }

    unsigned ukth;
    if (c >= K_SPARSE + 1 && c <= FAST_CAP) {
        // --- Phase 2 (fast): compact candidates (u > uT) to LDS. No atomics.
        unsigned pos = base;
#pragma unroll
        for (int i = 0; i < EPT; ++i) {
            if (u[i] > uT) list[pos++] = u[i];
        }
        if (t < 8) list[c + t] = 0u;   // pad so b128 tail reads see neutral values
        __syncthreads();               // B2: list complete

        // --- Phase 3 (fast): exact tie-aware rank-K select among c candidates.
        const int nq = (int)((c + 3) >> 2);
        const nuint4* listv = reinterpret_cast<const nuint4*>(list);
        for (int j = t; j < (int)c; j += NTHREADS) {
            const unsigned vj = list[j];
            unsigned g = 0, e = 0;
            for (int q = 0; q < nq; ++q) {
                const nuint4 ql = listv[q];    // broadcast read: all lanes same addr
                g += (ql.x > vj) + (ql.y > vj) + (ql.z > vj) + (ql.w > vj);
                e += (ql.x == vj) + (ql.y == vj) + (ql.z == vj) + (ql.w == vj);
            }
            if (g <= (unsigned)K_SPARSE && (unsigned)K_SPARSE < g + e)
                s_kth = vj;                    // unique value; benign same-value race
        }
        __syncthreads();               // B3: s_kth visible
        ukth = s_kth;
    } else {
        // --- Fallback (exact, fully general; ~never taken on N(0,1) data):
        // bitwise binary search for the largest v with |{u >= v}| >= K+1;
        // that v is exactly the mapped kth = sorted[n-1-K].
        unsigned prefix = 0u;
        for (int b = 31; b >= 0; --b) {
            const unsigned trial = prefix | (1u << b);
            unsigned c2 = 0;
#pragma unroll
            for (int i = 0; i < EPT; ++i) c2 += (u[i] >= trial) ? 1u : 0u;
#pragma unroll
            for (int off = 32; off >= 1; off >>= 1)
                c2 += __shfl_xor(c2, off, 64);       // wave reduce (all lanes)
            if (lane == 0) wtot[w] = c2;
            __syncthreads();
            const unsigned tot = wtot[0] + wtot[1];  // uniform across block
            if (tot >= K_SPARSE + 1) prefix = trial;
            __syncthreads();           // protect wtot before next bit
        }
        ukth = prefix;                 // identical in every thread
    }

    // --- Phase 4: masked nt-store. Mapped-domain compare == float compare
    // (strictly monotone bijection on non-NaN values); value via exact unmapf.
#pragma unroll
    for (int i = 0; i < VPT; ++i) {
        nfloat4 o;
        o.x = (u[i * 4 + 0] > ukth) ? unmapf(u[i * 4 + 0]) : 0.0f;
        o.y = (u[i * 4 + 1] > ukth) ? unmapf(u[i * 4 + 1]) : 0.0f;
        o.z = (u[i * 4 + 2] > ukth) ? unmapf(u[i * 4 + 2]) : 0.0f;
        o.w = (u[i * 4 + 3] > ukth) ? unmapf(u[i * 4 + 3]) : 0.0f;
        __builtin_nontemporal_store(o, &orow[t + i * NTHREADS]);
    }
}

extern "C" void kernel_launch(void* const* d_in, const int* in_sizes, int n_in,
                              void* d_out, int out_size, void* d_ws, size_t ws_size,
                              hipStream_t stream) {
    const float* x = (const float*)d_in[0];
    float* out = (float*)d_out;
    const int rows = in_sizes[0] / COLS;
    ksparse_select<<<rows, NTHREADS, 0, stream>>>(x, out, rows);
}